// Round 1
// baseline (1542.683 us; speedup 1.0000x reference)
//
#include <hip/hip_runtime.h>
#include <hip/hip_bf16.h>

// Problem constants
#define B_    32
#define IN_C  8
#define OUT_C 8
#define KK    3
#define MC    32
#define HH_   512
#define WW_   512

// ---------------------------------------------------------------------------
// Kernel A: hypernetwork, one block per batch sample b (32 blocks x 576 thr).
//   m1[c] = leaky( sum_j q[b][j]*wm1[c][j] + bm1[c] )   (j over 64)
//   m2[c] = leaky( sum_k m1[k]*wm2[c][k] + bm2[c] )
//   F[b][tap*8+o] = sum_c m2[c]*wt[c][(o*8+i)*9+kk] + bt[o*8+i],  tap=i*9+kk
//   bS[b][o] = sum_c m2[c]*wb[o][c] + bb[o]
// F layout: [b][i][kh][kw][o]  (o contiguous) -- matches conv kernel.
// ---------------------------------------------------------------------------
__global__ __launch_bounds__(576) void manifold_kernel(
    const float* __restrict__ q, const float* __restrict__ wm1,
    const float* __restrict__ bm1, const float* __restrict__ wm2,
    const float* __restrict__ bm2, const float* __restrict__ wt,
    const float* __restrict__ bt, const float* __restrict__ wb,
    const float* __restrict__ bb, float* __restrict__ F,
    float* __restrict__ bS)
{
    __shared__ float m1s[MC];
    __shared__ float m2s[MC];
    const int b = blockIdx.x;
    const int t = threadIdx.x;

    if (t < MC) {
        float s = 0.f;
        #pragma unroll 8
        for (int j = 0; j < 64; ++j)
            s += q[b * 64 + j] * wm1[t * 64 + j];
        s += bm1[t];
        m1s[t] = (s > 0.f) ? s : 0.01f * s;
    }
    __syncthreads();
    if (t < MC) {
        float s2 = 0.f;
        #pragma unroll
        for (int k = 0; k < MC; ++k)
            s2 += m1s[k] * wm2[t * MC + k];
        s2 += bm2[t];
        m2s[t] = (s2 > 0.f) ? s2 : 0.01f * s2;
    }
    __syncthreads();

    // one thread per filter value: t = tap*8 + o, tap = i*9 + kk
    {
        const int o   = t & 7;
        const int tap = t >> 3;
        const int i   = tap / 9;
        const int kk  = tap - i * 9;
        const int widx = (o * IN_C + i) * 9 + kk;
        float acc = bt[o * IN_C + i];
        #pragma unroll
        for (int cc = 0; cc < MC; ++cc)
            acc += m2s[cc] * wt[cc * 576 + widx];
        F[b * 576 + t] = acc;
    }

    if (t < OUT_C) {
        float acc = bb[t];
        #pragma unroll
        for (int cc = 0; cc < MC; ++cc)
            acc += m2s[cc] * wb[t * MC + cc];
        bS[b * OUT_C + t] = acc;
    }
}

// ---------------------------------------------------------------------------
// Kernel B: per-sample 3x3 conv, stride 1, pad 1 — NO LDS staging.
// Rationale (rocprof, prev round): LDS version was stall-bound (VALUBusy 53%,
// 8-way bank conflicts on the edge b32 reads = 2.97e7 conflict cycles, plus
// 4 full vmcnt(0)+barrier drains per block at only 44% occupancy).
// Per-channel vertical reuse window is ~1.7 KB -> L1 (32 KiB) absorbs the 3x
// vertical re-read; center loads are coalesced float4; halo scalars hit the
// same L1 lines. Filters are block-uniform -> s_load into SGPRs.
// No LDS, no barriers -> 6 blocks/CU (launch_bounds(256,6)), pure TLP
// latency hiding.
// Block = 256 threads -> output tile 64 wide x 16 tall, all 8 out channels.
// ---------------------------------------------------------------------------
__global__ __launch_bounds__(256, 6) void conv_main_kernel(
    const float* __restrict__ x, const float* __restrict__ F,
    const float* __restrict__ bS, float* __restrict__ y)
{
    const int b  = blockIdx.z;
    const int w0 = blockIdx.x * 64;
    const int h0 = blockIdx.y * 16;
    const int tid = threadIdx.x;
    const int tx = tid & 15;            // 0..15 -> 4-px group
    const int ty = tid >> 4;            // 0..15 -> row
    const int h  = h0 + ty;
    const int w  = w0 + tx * 4;

    const float* __restrict__ Fb = F + b * 576;
    const float* __restrict__ xb = x + (size_t)b * IN_C * HH_ * WW_;

    float acc[OUT_C][4];
    #pragma unroll
    for (int o = 0; o < OUT_C; ++o) {
        float bv = bS[b * OUT_C + o];
        #pragma unroll
        for (int p = 0; p < 4; ++p) acc[o][p] = bv;
    }

    #pragma unroll
    for (int i = 0; i < IN_C; ++i) {
        const float* __restrict__ xc = xb + (size_t)i * (HH_ * WW_);
        #pragma unroll
        for (int r = 0; r < KK; ++r) {
            const int hh = h - 1 + r;
            const bool rowok = ((unsigned)hh < (unsigned)HH_);
            const float* rp = xc + (ptrdiff_t)hh * WW_ + w;

            float4 xm = make_float4(0.f, 0.f, 0.f, 0.f);
            float xl = 0.f, xr = 0.f;
            if (rowok) {
                xm = *reinterpret_cast<const float4*>(rp);   // cols w..w+3
                if (w > 0)            xl = rp[-1];           // col w-1
                if (w + 4 < WW_)      xr = rp[4];            // col w+4
            }
            const float xv[6] = { xl, xm.x, xm.y, xm.z, xm.w, xr };

            #pragma unroll
            for (int kw = 0; kw < KK; ++kw) {
                #pragma unroll
                for (int o = 0; o < OUT_C; ++o) {
                    // block-uniform address -> s_load (SGPR operand)
                    const float f = Fb[(i * 9 + r * 3 + kw) * 8 + o];
                    #pragma unroll
                    for (int p = 0; p < 4; ++p)
                        acc[o][p] += xv[kw + p] * f;
                }
            }
        }
    }

    // coalesced float4 stores, one per out channel
    #pragma unroll
    for (int o = 0; o < OUT_C; ++o) {
        float4 v = make_float4(acc[o][0], acc[o][1], acc[o][2], acc[o][3]);
        float* yp = y + (((size_t)b * OUT_C + o) * HH_ + h) * WW_ + w;
        *reinterpret_cast<float4*>(yp) = v;
    }
}

// ---------------------------------------------------------------------------
extern "C" void kernel_launch(void* const* d_in, const int* in_sizes, int n_in,
                              void* d_out, int out_size, void* d_ws, size_t ws_size,
                              hipStream_t stream)
{
    const float* q   = (const float*)d_in[0];
    const float* x   = (const float*)d_in[1];
    const float* wm1 = (const float*)d_in[2];
    const float* bm1 = (const float*)d_in[3];
    const float* wm2 = (const float*)d_in[4];
    const float* bm2 = (const float*)d_in[5];
    const float* wt  = (const float*)d_in[6];
    const float* bt  = (const float*)d_in[7];
    const float* wb  = (const float*)d_in[8];
    const float* bb  = (const float*)d_in[9];
    float* out = (float*)d_out;

    float* Fw = (float*)d_ws;                  // 32*576 = 18432 floats
    float* bS = Fw + B_ * 576;                 // 32*8   = 256 floats

    manifold_kernel<<<B_, 576, 0, stream>>>(q, wm1, bm1, wm2, bm2, wt, bt, wb, bb, Fw, bS);

    dim3 grid(WW_ / 64, HH_ / 16, B_);
    conv_main_kernel<<<grid, 256, 0, stream>>>(x, Fw, bS, out);
}

// Round 2
// 959.948 us; speedup vs baseline: 1.6070x; 1.6070x over previous
//
#include <hip/hip_runtime.h>
#include <hip/hip_bf16.h>

// Problem constants
#define B_    32
#define IN_C  8
#define OUT_C 8
#define KK    3
#define MC    32
#define HH_   512
#define WW_   512

// ---------------------------------------------------------------------------
// Kernel A: hypernetwork, one block per batch sample b (32 blocks x 576 thr).
// ---------------------------------------------------------------------------
__global__ __launch_bounds__(576) void manifold_kernel(
    const float* __restrict__ q, const float* __restrict__ wm1,
    const float* __restrict__ bm1, const float* __restrict__ wm2,
    const float* __restrict__ bm2, const float* __restrict__ wt,
    const float* __restrict__ bt, const float* __restrict__ wb,
    const float* __restrict__ bb, float* __restrict__ F,
    float* __restrict__ bS)
{
    __shared__ float m1s[MC];
    __shared__ float m2s[MC];
    const int b = blockIdx.x;
    const int t = threadIdx.x;

    if (t < MC) {
        float s = 0.f;
        #pragma unroll 8
        for (int j = 0; j < 64; ++j)
            s += q[b * 64 + j] * wm1[t * 64 + j];
        s += bm1[t];
        m1s[t] = (s > 0.f) ? s : 0.01f * s;
    }
    __syncthreads();
    if (t < MC) {
        float s2 = 0.f;
        #pragma unroll
        for (int k = 0; k < MC; ++k)
            s2 += m1s[k] * wm2[t * MC + k];
        s2 += bm2[t];
        m2s[t] = (s2 > 0.f) ? s2 : 0.01f * s2;
    }
    __syncthreads();

    // one thread per filter value: t = tap*8 + o, tap = i*9 + kk
    {
        const int o   = t & 7;
        const int tap = t >> 3;
        const int i   = tap / 9;
        const int kk  = tap - i * 9;
        const int widx = (o * IN_C + i) * 9 + kk;
        float acc = bt[o * IN_C + i];
        #pragma unroll
        for (int cc = 0; cc < MC; ++cc)
            acc += m2s[cc] * wt[cc * 576 + widx];
        F[b * 576 + t] = acc;
    }

    if (t < OUT_C) {
        float acc = bb[t];
        #pragma unroll
        for (int cc = 0; cc < MC; ++cc)
            acc += m2s[cc] * wb[t * MC + cc];
        bS[b * OUT_C + t] = acc;
    }
}

// ---------------------------------------------------------------------------
// Kernel B: per-sample 3x3 conv, stride 1, pad 1 — NO LDS staging, direct
// global reads (L1/L2 absorb the 3x vertical re-read; center loads are
// coalesced float4; filters are block-uniform -> s_load).
//
// ROUND-1 POST-MORTEM: __launch_bounds__(256,6) capped VGPRs at 40 -> the
// 32-float accumulator array spilled to scratch -> 4.3 GB of scratch traffic
// (WRITE_SIZE 2.6 GB vs 268 MB output), 5x regression. The no-LDS structure
// itself was never tested. Fix: (256,4) -> VGPR cap 128; round-0's LDS
// version held these accumulators in 64 VGPRs, so no spill at this bound.
// ---------------------------------------------------------------------------
__global__ __launch_bounds__(256, 4) void conv_main_kernel(
    const float* __restrict__ x, const float* __restrict__ F,
    const float* __restrict__ bS, float* __restrict__ y)
{
    const int b  = blockIdx.z;
    const int w0 = blockIdx.x * 64;
    const int h0 = blockIdx.y * 16;
    const int tid = threadIdx.x;
    const int tx = tid & 15;            // 0..15 -> 4-px group
    const int ty = tid >> 4;            // 0..15 -> row
    const int h  = h0 + ty;
    const int w  = w0 + tx * 4;

    const float* __restrict__ Fb = F + b * 576;
    const float* __restrict__ xb = x + (size_t)b * IN_C * HH_ * WW_;

    float acc[OUT_C][4];
    #pragma unroll
    for (int o = 0; o < OUT_C; ++o) {
        float bv = bS[b * OUT_C + o];
        #pragma unroll
        for (int p = 0; p < 4; ++p) acc[o][p] = bv;
    }

    #pragma unroll
    for (int i = 0; i < IN_C; ++i) {
        const float* __restrict__ xc = xb + (size_t)i * (HH_ * WW_);
        #pragma unroll
        for (int r = 0; r < KK; ++r) {
            const int hh = h - 1 + r;
            const bool rowok = ((unsigned)hh < (unsigned)HH_);
            const float* rp = xc + (ptrdiff_t)hh * WW_ + w;

            float4 xm = make_float4(0.f, 0.f, 0.f, 0.f);
            float xl = 0.f, xr = 0.f;
            if (rowok) {
                xm = *reinterpret_cast<const float4*>(rp);   // cols w..w+3
                if (w > 0)            xl = rp[-1];           // col w-1
                if (w + 4 < WW_)      xr = rp[4];            // col w+4
            }
            const float xv[6] = { xl, xm.x, xm.y, xm.z, xm.w, xr };

            #pragma unroll
            for (int kw = 0; kw < KK; ++kw) {
                #pragma unroll
                for (int o = 0; o < OUT_C; ++o) {
                    // block-uniform address -> s_load (SGPR operand)
                    const float f = Fb[(i * 9 + r * 3 + kw) * 8 + o];
                    #pragma unroll
                    for (int p = 0; p < 4; ++p)
                        acc[o][p] += xv[kw + p] * f;
                }
            }
        }
    }

    // coalesced float4 stores, one per out channel
    #pragma unroll
    for (int o = 0; o < OUT_C; ++o) {
        float4 v = make_float4(acc[o][0], acc[o][1], acc[o][2], acc[o][3]);
        float* yp = y + (((size_t)b * OUT_C + o) * HH_ + h) * WW_ + w;
        *reinterpret_cast<float4*>(yp) = v;
    }
}

// ---------------------------------------------------------------------------
extern "C" void kernel_launch(void* const* d_in, const int* in_sizes, int n_in,
                              void* d_out, int out_size, void* d_ws, size_t ws_size,
                              hipStream_t stream)
{
    const float* q   = (const float*)d_in[0];
    const float* x   = (const float*)d_in[1];
    const float* wm1 = (const float*)d_in[2];
    const float* bm1 = (const float*)d_in[3];
    const float* wm2 = (const float*)d_in[4];
    const float* bm2 = (const float*)d_in[5];
    const float* wt  = (const float*)d_in[6];
    const float* bt  = (const float*)d_in[7];
    const float* wb  = (const float*)d_in[8];
    const float* bb  = (const float*)d_in[9];
    float* out = (float*)d_out;

    float* Fw = (float*)d_ws;                  // 32*576 = 18432 floats
    float* bS = Fw + B_ * 576;                 // 32*8   = 256 floats

    manifold_kernel<<<B_, 576, 0, stream>>>(q, wm1, bm1, wm2, bm2, wt, bt, wb, bb, Fw, bS);

    dim3 grid(WW_ / 64, HH_ / 16, B_);
    conv_main_kernel<<<grid, 256, 0, stream>>>(x, Fw, bS, out);
}

// Round 3
// 547.540 us; speedup vs baseline: 2.8175x; 1.7532x over previous
//
#include <hip/hip_runtime.h>
#include <hip/hip_bf16.h>

// Problem constants
#define B_    32
#define IN_C  8
#define OUT_C 8
#define KK    3
#define MC    32
#define HH_   512
#define WW_   512

// ---------------------------------------------------------------------------
// Kernel A: hypernetwork, one block per batch sample b (32 blocks x 576 thr).
// ---------------------------------------------------------------------------
__global__ __launch_bounds__(576) void manifold_kernel(
    const float* __restrict__ q, const float* __restrict__ wm1,
    const float* __restrict__ bm1, const float* __restrict__ wm2,
    const float* __restrict__ bm2, const float* __restrict__ wt,
    const float* __restrict__ bt, const float* __restrict__ wb,
    const float* __restrict__ bb, float* __restrict__ F,
    float* __restrict__ bS)
{
    __shared__ float m1s[MC];
    __shared__ float m2s[MC];
    const int b = blockIdx.x;
    const int t = threadIdx.x;

    if (t < MC) {
        float s = 0.f;
        #pragma unroll 8
        for (int j = 0; j < 64; ++j)
            s += q[b * 64 + j] * wm1[t * 64 + j];
        s += bm1[t];
        m1s[t] = (s > 0.f) ? s : 0.01f * s;
    }
    __syncthreads();
    if (t < MC) {
        float s2 = 0.f;
        #pragma unroll
        for (int k = 0; k < MC; ++k)
            s2 += m1s[k] * wm2[t * MC + k];
        s2 += bm2[t];
        m2s[t] = (s2 > 0.f) ? s2 : 0.01f * s2;
    }
    __syncthreads();

    // one thread per filter value: t = tap*8 + o, tap = i*9 + kk
    {
        const int o   = t & 7;
        const int tap = t >> 3;
        const int i   = tap / 9;
        const int kk  = tap - i * 9;
        const int widx = (o * IN_C + i) * 9 + kk;
        float acc = bt[o * IN_C + i];
        #pragma unroll
        for (int cc = 0; cc < MC; ++cc)
            acc += m2s[cc] * wt[cc * 576 + widx];
        F[b * 576 + t] = acc;
    }

    if (t < OUT_C) {
        float acc = bb[t];
        #pragma unroll
        for (int cc = 0; cc < MC; ++cc)
            acc += m2s[cc] * wb[t * MC + cc];
        bS[b * OUT_C + t] = acc;
    }
}

// ---------------------------------------------------------------------------
// Kernel B: per-sample 3x3 conv, stride 1, pad 1 — direct global reads.
//
// ROUND-2 POST-MORTEM: full unroll of the channel loop put 72 global loads
// in the unrolled body; the scheduler hoisted load clusters, live ranges
// blew past the allocator's 64-VGPR target, and accumulators spilled to
// scratch in the hot loop -> WRITE_SIZE 1.43 GB (5.3x output) and
// FETCH_SIZE 820 MB (3x input: 38 KB 8-channel working set also blew L1,
// so vertical taps missed). Fix: #pragma unroll 1 on the channel loop
// (only ~9 loads in flight; 4.7 KB per-channel window is L1-resident) and
// no min-waves hint so the allocator isn't pushed into spilling.
// ---------------------------------------------------------------------------
__global__ __launch_bounds__(256) void conv_main_kernel(
    const float* __restrict__ x, const float* __restrict__ F,
    const float* __restrict__ bS, float* __restrict__ y)
{
    const int b  = blockIdx.z;
    const int w0 = blockIdx.x * 64;
    const int h0 = blockIdx.y * 16;
    const int tid = threadIdx.x;
    const int tx = tid & 15;            // 0..15 -> 4-px group
    const int ty = tid >> 4;            // 0..15 -> row
    const int h  = h0 + ty;
    const int w  = w0 + tx * 4;

    const float* __restrict__ Fb = F + b * 576;
    const float* __restrict__ xb = x + (size_t)b * IN_C * HH_ * WW_;

    float acc[OUT_C][4];
    #pragma unroll
    for (int o = 0; o < OUT_C; ++o) {
        float bv = bS[b * OUT_C + o];
        #pragma unroll
        for (int p = 0; p < 4; ++p) acc[o][p] = bv;
    }

    #pragma unroll 1                    // KEY: one channel at a time
    for (int i = 0; i < IN_C; ++i) {
        const float* __restrict__ xc = xb + (size_t)i * (HH_ * WW_);
        #pragma unroll
        for (int r = 0; r < KK; ++r) {
            const int hh = h - 1 + r;
            const bool rowok = ((unsigned)hh < (unsigned)HH_);
            const float* rp = xc + (ptrdiff_t)hh * WW_ + w;

            float4 xm = make_float4(0.f, 0.f, 0.f, 0.f);
            float xl = 0.f, xr = 0.f;
            if (rowok) {
                xm = *reinterpret_cast<const float4*>(rp);   // cols w..w+3
                if (w > 0)            xl = rp[-1];           // col w-1
                if (w + 4 < WW_)      xr = rp[4];            // col w+4
            }
            const float xv[6] = { xl, xm.x, xm.y, xm.z, xm.w, xr };

            #pragma unroll
            for (int kw = 0; kw < KK; ++kw) {
                #pragma unroll
                for (int o = 0; o < OUT_C; ++o) {
                    // block-uniform address -> s_load (SGPR operand)
                    const float f = Fb[(i * 9 + r * 3 + kw) * 8 + o];
                    #pragma unroll
                    for (int p = 0; p < 4; ++p)
                        acc[o][p] += xv[kw + p] * f;
                }
            }
        }
    }

    // coalesced float4 stores, one per out channel
    #pragma unroll
    for (int o = 0; o < OUT_C; ++o) {
        float4 v = make_float4(acc[o][0], acc[o][1], acc[o][2], acc[o][3]);
        float* yp = y + (((size_t)b * OUT_C + o) * HH_ + h) * WW_ + w;
        *reinterpret_cast<float4*>(yp) = v;
    }
}

// ---------------------------------------------------------------------------
extern "C" void kernel_launch(void* const* d_in, const int* in_sizes, int n_in,
                              void* d_out, int out_size, void* d_ws, size_t ws_size,
                              hipStream_t stream)
{
    const float* q   = (const float*)d_in[0];
    const float* x   = (const float*)d_in[1];
    const float* wm1 = (const float*)d_in[2];
    const float* bm1 = (const float*)d_in[3];
    const float* wm2 = (const float*)d_in[4];
    const float* bm2 = (const float*)d_in[5];
    const float* wt  = (const float*)d_in[6];
    const float* bt  = (const float*)d_in[7];
    const float* wb  = (const float*)d_in[8];
    const float* bb  = (const float*)d_in[9];
    float* out = (float*)d_out;

    float* Fw = (float*)d_ws;                  // 32*576 = 18432 floats
    float* bS = Fw + B_ * 576;                 // 32*8   = 256 floats

    manifold_kernel<<<B_, 576, 0, stream>>>(q, wm1, bm1, wm2, bm2, wt, bt, wb, bb, Fw, bS);

    dim3 grid(WW_ / 64, HH_ / 16, B_);
    conv_main_kernel<<<grid, 256, 0, stream>>>(x, Fw, bS, out);
}